// Round 7
// baseline (470.114 us; speedup 1.0000x reference)
//
#include <hip/hip_runtime.h>

// LSTM autoencoder: 4 layers 64->64, B=512, T=256 — fused single-launch,
// MFMA recurrence, cross-layer pipeline, split v/h matvec.
//
// 256 blocks x 512 threads. Block = 2 batch elements x all 4 layers.
// Wave w = (layer L = w>>1, unit-half mh = w&1). Tick tau: layer L at
// t = tau - L. Per tick:
//   P1: C = Cv + Whh.h(t-1)   (16 MFMA; Cv = Wih.v(t) from last tick's P3)
//       -> assemble (i,f,g,o) float4 per unit, write G2 (gate-split tiles:
//          wave owns ALL 4 gates of units [mh*32, mh*32+32))
//   P2: epilogue, 1 unit/thread: 1x ds_read_b128 of gates + bias regs,
//       c/h update, h -> Hb (f16, parity ping-pong), L3 writes out.
//   P3: Cv = Wih.v(t+1)       (16 MFMA; v = x prefetch regs for L0, else
//       h_{L-1}(t+1) just written this tick by layer L-1)
// x prefetch: raw float4 regs loaded 1 tick ahead (P1), converted to f16
// frags the following tick — all statically indexed, no parity arrays.

typedef _Float16 f16x8 __attribute__((ext_vector_type(8)));
typedef float    f32x4 __attribute__((ext_vector_type(4)));

#define TSEQ 256

__device__ __forceinline__ float fast_rcp(float x) { return __builtin_amdgcn_rcpf(x); }
__device__ __forceinline__ float sigm(float x) { return fast_rcp(1.0f + __expf(-x)); }
__device__ __forceinline__ float tanh_fast(float x) {
    return 2.0f * fast_rcp(1.0f + __expf(-2.0f * x)) - 1.0f;
}
__device__ __forceinline__ f16x8 cvt8(float4 a, float4 b) {
    f16x8 f;
    f[0] = (_Float16)a.x; f[1] = (_Float16)a.y; f[2] = (_Float16)a.z; f[3] = (_Float16)a.w;
    f[4] = (_Float16)b.x; f[5] = (_Float16)b.y; f[6] = (_Float16)b.z; f[7] = (_Float16)b.w;
    return f;
}

__global__ __launch_bounds__(512, 2)
void lstm_fused3(const float* __restrict__ x,     // [512, 256, 64]
                 float* __restrict__ out,         // [512, 256, 64]
                 const float* __restrict__ Wih0, const float* __restrict__ Whh0,
                 const float* __restrict__ bi0,  const float* __restrict__ bh0,
                 const float* __restrict__ Wih1, const float* __restrict__ Whh1,
                 const float* __restrict__ bi1,  const float* __restrict__ bh1,
                 const float* __restrict__ Wih2, const float* __restrict__ Whh2,
                 const float* __restrict__ bi2,  const float* __restrict__ bh2,
                 const float* __restrict__ Wih3, const float* __restrict__ Whh3,
                 const float* __restrict__ bi3,  const float* __restrict__ bh3)
{
    __shared__ float4   G2[4 * 2 * 64];        // [L][el][unit] -> (i,f,g,o), 8 KB
    __shared__ _Float16 Hb[4 * 2 * 2 * 64];    // [L][parity][el][64], 2 KB

    const int tid  = threadIdx.x;
    const int wave = tid >> 6;
    const int lane = tid & 63;
    const int L    = wave >> 1;       // layer
    const int mh   = wave & 1;        // unit-half: owns units [mh*32, mh*32+32)
    const int q    = lane >> 4;       // quad
    const int n    = lane & 15;       // MFMA col
    const int elB  = n & 1;           // element fed into B-frag col n
    const int b0   = blockIdx.x * 2;

    const float* Wih = (L == 0) ? Wih0 : (L == 1) ? Wih1 : (L == 2) ? Wih2 : Wih3;
    const float* Whh = (L == 0) ? Whh0 : (L == 1) ? Whh1 : (L == 2) ? Whh2 : Whh3;
    const float* bi  = (L == 0) ? bi0  : (L == 1) ? bi1  : (L == 2) ? bi2  : bi3;
    const float* bh  = (L == 0) ? bh0  : (L == 1) ? bh1  : (L == 2) ? bh2  : bh3;

    // ---- A-fragments, gate-split tiles: ti = g*2+j covers rows ----
    // [g*64 + mh*32 + j*16, +16)  -> wave owns all 4 gates of its 32 units.
    // A layout: A[m = lane&15][k = q*8 + jj]
    f16x8 Ahh[8][2], Aih[8][2];
#pragma unroll
    for (int g = 0; g < 4; ++g) {
#pragma unroll
        for (int j = 0; j < 2; ++j) {
            const int ti  = g * 2 + j;
            const int row = g * 64 + mh * 32 + j * 16 + n;
#pragma unroll
            for (int c = 0; c < 2; ++c) {
                const float* ph = Whh + row * 64 + c * 32 + q * 8;
                const float* pi = Wih + row * 64 + c * 32 + q * 8;
                f16x8 fh, fi;
#pragma unroll
                for (int k = 0; k < 8; ++k) { fh[k] = (_Float16)ph[k]; fi[k] = (_Float16)pi[k]; }
                Ahh[ti][c] = fh;
                Aih[ti][c] = fi;
            }
        }
    }

    // ---- epilogue bias (thread owns unit=lane, el=mh) ----
    float4 be;
    be.x = bi[lane]       + bh[lane];
    be.y = bi[64 + lane]  + bh[64 + lane];
    be.z = bi[128 + lane] + bh[128 + lane];
    be.w = bi[192 + lane] + bh[192 + lane];

    // ---- zero hidden state (both parities) ----
    ((int*)Hb)[tid] = 0;

    // ---- x prefetch (L0 only): raw = next-next step, xf = next step ----
    const float* xbase = x + ((size_t)(b0 + elB) * TSEQ) * 64 + q * 8;
    float4 r0, r1, r2, r3;
    f16x8 xf0, xf1;
    if (L == 0) {
        const float* p = xbase;                        // t = 0
        r0 = *(const float4*)(p);      r1 = *(const float4*)(p + 4);
        r2 = *(const float4*)(p + 32); r3 = *(const float4*)(p + 36);
        xf0 = cvt8(r0, r1); xf1 = cvt8(r2, r3);        // x(0)
        p = xbase + 64;                                // t = 1
        r0 = *(const float4*)(p);      r1 = *(const float4*)(p + 4);
        r2 = *(const float4*)(p + 32); r3 = *(const float4*)(p + 36);
    }

    // ---- prologue P3(tau=-1): Cv = Wih.v(0); only L0 has v(0) ----
    const f32x4 z4 = {0.f, 0.f, 0.f, 0.f};
    f32x4 Cv[8];
#pragma unroll
    for (int ti = 0; ti < 8; ++ti) Cv[ti] = z4;
    if (L == 0) {
#pragma unroll
        for (int ti = 0; ti < 8; ++ti) {
            f32x4 c = __builtin_amdgcn_mfma_f32_16x16x32_f16(Aih[ti][0], xf0, z4, 0, 0, 0);
            Cv[ti]  = __builtin_amdgcn_mfma_f32_16x16x32_f16(Aih[ti][1], xf1, c,  0, 0, 0);
        }
    }

    float cst = 0.0f;
    float* outp = out + ((size_t)(b0 + mh) * TSEQ) * 64 + lane;   // L==3 only

    __syncthreads();

    for (int tau = 0; tau < TSEQ + 3; ++tau) {
        const int  t    = tau - L;
        const bool act  = (unsigned)t < TSEQ;
        const bool actv = (unsigned)(t + 1) < TSEQ;
        const int  pr   = (tau + 1) & 1;
        const int  pw   = tau & 1;

        // ---------------- P1: h-half MFMA + gate assembly ----------------
        if (act) {
            if (L == 0) {
                xf0 = cvt8(r0, r1); xf1 = cvt8(r2, r3);          // x(tau+1)
                if (tau + 2 < TSEQ) {                            // load x(tau+2)
                    const float* p = xbase + (tau + 2) * 64;
                    r0 = *(const float4*)(p);      r1 = *(const float4*)(p + 4);
                    r2 = *(const float4*)(p + 32); r3 = *(const float4*)(p + 36);
                }
            }
            const _Float16* hp = Hb + ((L * 2 + pr) * 2 + elB) * 64;
            f16x8 hf0 = *(const f16x8*)(hp + q * 8);
            f16x8 hf1 = *(const f16x8*)(hp + 32 + q * 8);

            f32x4 C[8];
#pragma unroll
            for (int ti = 0; ti < 8; ++ti) {
                f32x4 c = __builtin_amdgcn_mfma_f32_16x16x32_f16(Ahh[ti][0], hf0, Cv[ti], 0, 0, 0);
                C[ti]   = __builtin_amdgcn_mfma_f32_16x16x32_f16(Ahh[ti][1], hf1, c,      0, 0, 0);
            }
            if (n < 2) {
#pragma unroll
                for (int j = 0; j < 2; ++j) {
#pragma unroll
                    for (int r = 0; r < 4; ++r) {
                        float4 st;
                        st.x = C[0 + j][r];   // gate i
                        st.y = C[2 + j][r];   // gate f
                        st.z = C[4 + j][r];   // gate g
                        st.w = C[6 + j][r];   // gate o
                        const int u = mh * 32 + j * 16 + q * 4 + r;
                        G2[(L * 2 + n) * 64 + u] = st;
                    }
                }
            }
        }
        __syncthreads();

        // ---------------- P2: epilogue (unit = lane, el = mh) ----------------
        if (act) {
            float4 gv = G2[(L * 2 + mh) * 64 + lane];
            float gi = sigm(gv.x + be.x);
            float gf = sigm(gv.y + be.y);
            float gg = tanh_fast(gv.z + be.z);
            float go = sigm(gv.w + be.w);
            cst = gf * cst + gi * gg;
            float h = go * tanh_fast(cst);
            if (L == 3) outp[t * 64] = h;
            Hb[((L * 2 + pw) * 2 + mh) * 64 + lane] = (_Float16)h;
        }
        __syncthreads();

        // ---------------- P3: v-half MFMA for t+1 ----------------
        if (actv) {
            f16x8 vf0, vf1;
            if (L == 0) {
                vf0 = xf0; vf1 = xf1;                           // x(tau+1)
            } else {
                const _Float16* vp = Hb + (((L - 1) * 2 + pw) * 2 + elB) * 64;
                vf0 = *(const f16x8*)(vp + q * 8);
                vf1 = *(const f16x8*)(vp + 32 + q * 8);
            }
#pragma unroll
            for (int ti = 0; ti < 8; ++ti) {
                f32x4 c = __builtin_amdgcn_mfma_f32_16x16x32_f16(Aih[ti][0], vf0, z4, 0, 0, 0);
                Cv[ti]  = __builtin_amdgcn_mfma_f32_16x16x32_f16(Aih[ti][1], vf1, c,  0, 0, 0);
            }
        }
    }
}

extern "C" void kernel_launch(void* const* d_in, const int* in_sizes, int n_in,
                              void* d_out, int out_size, void* d_ws, size_t ws_size,
                              hipStream_t stream) {
    const float* x = (const float*)d_in[0];
    float* out = (float*)d_out;

    lstm_fused3<<<256, 512, 0, stream>>>(
        x, out,
        (const float*)d_in[1],  (const float*)d_in[2],
        (const float*)d_in[3],  (const float*)d_in[4],
        (const float*)d_in[5],  (const float*)d_in[6],
        (const float*)d_in[7],  (const float*)d_in[8],
        (const float*)d_in[9],  (const float*)d_in[10],
        (const float*)d_in[11], (const float*)d_in[12],
        (const float*)d_in[13], (const float*)d_in[14],
        (const float*)d_in[15], (const float*)d_in[16]);
}